// Round 1
// baseline (3738.382 us; speedup 1.0000x reference)
//
#include <hip/hip_runtime.h>
#include <hip/hip_bf16.h>
#include <math.h>

// Problem constants
#define B_ 32
#define T_ 4096
#define D_ 256
#define H_ 64
#define A_ 259
#define K_ 256
#define M_ 1024
#define P_ 16
#define STEP_ 273   // idx[i] = 273*i exactly (4095/15)

// ---------------------------------------------------------------------------
// K1: sal[b,t] = sigmoid(relu(x@W1+b1)@W2 + b2), plus y_star write.
// One thread per row (256 threads/block). W1 (64KB) staged in LDS; all W1
// reads are wave-uniform broadcasts (conflict-free). x row read as float4
// with one-chunk-ahead prefetch to hide HBM latency behind 1024 FMAs.
// ---------------------------------------------------------------------------
__global__ __launch_bounds__(256, 2) void k1_sal(
    const float* __restrict__ x, const float* __restrict__ W1,
    const float* __restrict__ b1, const float* __restrict__ W2,
    const float* __restrict__ b2, float* __restrict__ sal,
    float* __restrict__ ystar)
{
    __shared__ float w1s[D_ * H_];   // [d][j], 64 KB
    __shared__ float w2s[H_];
    __shared__ float b1s[H_];
    {
        const float4* g = (const float4*)W1;
        float4* l = (float4*)w1s;
        #pragma unroll
        for (int i = 0; i < 16; ++i) l[threadIdx.x + i * 256] = g[threadIdx.x + i * 256];
        if (threadIdx.x < H_) {
            w2s[threadIdx.x] = W2[threadIdx.x];
            b1s[threadIdx.x] = b1[threadIdx.x];
        }
    }
    __syncthreads();

    int row = blockIdx.x * 256 + threadIdx.x;
    const float4* xr = (const float4*)(x + (size_t)row * D_);

    float h[H_];
    #pragma unroll
    for (int j = 0; j < H_; ++j) h[j] = b1s[j];

    // 16 chunks of 16 d-values (4 float4s), software prefetch one chunk ahead
    float4 buf[4];
    #pragma unroll
    for (int q = 0; q < 4; ++q) buf[q] = xr[q];

    for (int ch = 0; ch < 16; ++ch) {
        float4 nbuf[4];
        if (ch < 15) {
            #pragma unroll
            for (int q = 0; q < 4; ++q) nbuf[q] = xr[(ch + 1) * 4 + q];
        }
        #pragma unroll
        for (int q = 0; q < 4; ++q) {
            const int d0 = ch * 16 + q * 4;
            const float4 xv = buf[q];
            const float* wb = &w1s[d0 * H_];
            #pragma unroll
            for (int j4 = 0; j4 < 16; ++j4) {
                const float4 a0 = *(const float4*)(wb + 0 * H_ + j4 * 4);
                const float4 a1 = *(const float4*)(wb + 1 * H_ + j4 * 4);
                const float4 a2 = *(const float4*)(wb + 2 * H_ + j4 * 4);
                const float4 a3 = *(const float4*)(wb + 3 * H_ + j4 * 4);
                h[j4*4+0] = fmaf(xv.w, a3.x, fmaf(xv.z, a2.x, fmaf(xv.y, a1.x, fmaf(xv.x, a0.x, h[j4*4+0]))));
                h[j4*4+1] = fmaf(xv.w, a3.y, fmaf(xv.z, a2.y, fmaf(xv.y, a1.y, fmaf(xv.x, a0.y, h[j4*4+1]))));
                h[j4*4+2] = fmaf(xv.w, a3.z, fmaf(xv.z, a2.z, fmaf(xv.y, a1.z, fmaf(xv.x, a0.z, h[j4*4+2]))));
                h[j4*4+3] = fmaf(xv.w, a3.w, fmaf(xv.z, a2.w, fmaf(xv.y, a1.w, fmaf(xv.x, a0.w, h[j4*4+3]))));
            }
        }
        if (ch < 15) {
            #pragma unroll
            for (int q = 0; q < 4; ++q) buf[q] = nbuf[q];
        }
    }

    float score = b2[0];
    #pragma unroll
    for (int j = 0; j < H_; ++j) score = fmaf(fmaxf(h[j], 0.f), w2s[j], score);
    float s = 1.f / (1.f + __expf(-score));
    sal[row] = s;

    int t = row & (T_ - 1);
    ystar[row] = (t % STEP_ == 0) ? 1.f : 0.f;
}

// ---------------------------------------------------------------------------
// K2: per-batch inclusive cumsum of sal, sampled at the 16 idx positions.
// One block per batch; 16 values/thread sequential scan + Hillis-Steele over
// 256 thread totals.
// ---------------------------------------------------------------------------
__global__ __launch_bounds__(256) void k2_scan(
    const float* __restrict__ sal, float* __restrict__ cumsel)
{
    __shared__ float vals[T_];
    __shared__ float tsum[256];
    const int b = blockIdx.x;
    const int t = threadIdx.x;

    const float4* sp = (const float4*)(sal + (size_t)b * T_);
    float v[16];
    #pragma unroll
    for (int q = 0; q < 4; ++q) {
        float4 f = sp[t * 4 + q];
        v[q*4+0] = f.x; v[q*4+1] = f.y; v[q*4+2] = f.z; v[q*4+3] = f.w;
    }
    float run = 0.f;
    #pragma unroll
    for (int k = 0; k < 16; ++k) { run += v[k]; v[k] = run; }

    tsum[t] = run;
    __syncthreads();
    float val = run;
    for (int off = 1; off < 256; off <<= 1) {
        float add = (t >= off) ? tsum[t - off] : 0.f;
        __syncthreads();
        val += add;
        tsum[t] = val;
        __syncthreads();
    }
    const float offset = val - run;   // exclusive prefix of thread totals
    #pragma unroll
    for (int k = 0; k < 16; ++k) vals[t * 16 + k] = offset + v[k];
    __syncthreads();
    if (t < P_) cumsel[b * P_ + t] = vals[STEP_ * t] * (1.0f / (float)T_);
}

// ---------------------------------------------------------------------------
// K3a: lifted = tanh(z @ Wl + bl) for the 512 selected rows. 4 rows per block
// (Wl global reads coalesced across k=threadIdx, amortized over 4 rows).
// ---------------------------------------------------------------------------
__global__ __launch_bounds__(256) void k3a_lift(
    const float* __restrict__ x, const float* __restrict__ sal,
    const float* __restrict__ cumsel, const float* __restrict__ Wl,
    const float* __restrict__ bl, const float* __restrict__ mu,
    const float* __restrict__ sigma, float* __restrict__ lift)
{
    __shared__ float z[4][260];
    __shared__ float red[4];
    const int t = threadIdx.x;

    #pragma unroll 1
    for (int r = 0; r < 4; ++r) {
        const int s = blockIdx.x * 4 + r;
        const int b = s >> 4, i = s & 15;
        const int pos = STEP_ * i;
        const float* xrow = x + ((size_t)b * T_ + pos) * D_;
        const float xv = xrow[t];
        const float sv = sal[b * T_ + pos];
        const float tn = (float)pos * (1.0f / (float)T_);
        const float cv = cumsel[b * P_ + i];

        float p = xv * xv;
        if (t == 0) p += sv * sv + tn * tn + cv * cv;
        // block reduction
        float w = p;
        #pragma unroll
        for (int off = 32; off > 0; off >>= 1) w += __shfl_down(w, off, 64);
        __syncthreads();                     // protect red[] reuse across r
        if ((t & 63) == 0) red[t >> 6] = w;
        __syncthreads();
        const float ss = red[0] + red[1] + red[2] + red[3];
        const float inv = 1.0f / (sqrtf(ss) + 1e-6f);

        z[r][t] = (xv * inv - mu[t]) / sigma[t];
        if (t < 3) {
            const float e = (t == 0) ? sv : (t == 1) ? tn : cv;
            z[r][256 + t] = (e * inv - mu[256 + t]) / sigma[256 + t];
        }
    }
    __syncthreads();

    const int k = t;
    float acc0 = bl[k];
    float acc1 = acc0, acc2 = acc0, acc3 = acc0;
    #pragma unroll 4
    for (int a = 0; a < A_; ++a) {
        const float w = Wl[a * K_ + k];      // coalesced across threads
        acc0 = fmaf(z[0][a], w, acc0);       // z reads are LDS broadcasts
        acc1 = fmaf(z[1][a], w, acc1);
        acc2 = fmaf(z[2][a], w, acc2);
        acc3 = fmaf(z[3][a], w, acc3);
    }
    const size_t base = (size_t)blockIdx.x * 4 * K_;
    lift[base + 0 * K_ + k] = tanhf(acc0);
    lift[base + 1 * K_ + k] = tanhf(acc1);
    lift[base + 2 * K_ + k] = tanhf(acc2);
    lift[base + 3 * K_ + k] = tanhf(acc3);
}

// ---------------------------------------------------------------------------
// K3b: tokens = lifted @ Wp + bp. Block = (batch, row-half of 8, m-tile of
// 256). lifted rows in LDS (broadcast reads); Wp reads coalesced.
// ---------------------------------------------------------------------------
__global__ __launch_bounds__(256) void k3b_tok(
    const float* __restrict__ lift, const float* __restrict__ Wp,
    const float* __restrict__ bp, float* __restrict__ tokens)
{
    __shared__ float ls[8 * K_];
    const int t = threadIdx.x;
    const int mt = blockIdx.x & 3;
    const int rh = (blockIdx.x >> 2) & 1;
    const int b  = blockIdx.x >> 3;
    const int s0 = b * P_ + rh * 8;

    const float4* lg = (const float4*)(lift + (size_t)s0 * K_);
    float4* lsl = (float4*)ls;
    #pragma unroll
    for (int q = 0; q < 2; ++q) lsl[t + q * 256] = lg[t + q * 256];
    __syncthreads();

    const int m = mt * 256 + t;
    float acc[8];
    const float bv = bp[m];
    #pragma unroll
    for (int r = 0; r < 8; ++r) acc[r] = bv;

    #pragma unroll 4
    for (int c = 0; c < K_; ++c) {
        const float w = Wp[c * M_ + m];      // coalesced across threads
        #pragma unroll
        for (int r = 0; r < 8; ++r) acc[r] = fmaf(ls[r * K_ + c], w, acc[r]);
    }
    #pragma unroll
    for (int r = 0; r < 8; ++r) tokens[(size_t)(s0 + r) * M_ + m] = acc[r];
}

// ---------------------------------------------------------------------------
extern "C" void kernel_launch(void* const* d_in, const int* in_sizes, int n_in,
                              void* d_out, int out_size, void* d_ws, size_t ws_size,
                              hipStream_t stream)
{
    (void)in_sizes; (void)n_in; (void)out_size; (void)ws_size;
    const float* x  = (const float*)d_in[0];
    const float* W1 = (const float*)d_in[1];
    const float* b1 = (const float*)d_in[2];
    const float* W2 = (const float*)d_in[3];
    const float* b2 = (const float*)d_in[4];
    const float* Wl = (const float*)d_in[5];
    const float* bl = (const float*)d_in[6];
    const float* mu = (const float*)d_in[7];
    const float* sg = (const float*)d_in[8];
    const float* Wp = (const float*)d_in[9];
    const float* bp = (const float*)d_in[10];

    float* out    = (float*)d_out;
    float* tokens = out;                       // B*P*M = 524288 floats
    float* ystar  = out + (size_t)B_ * P_ * M_; // B*T = 131072 floats

    float* ws     = (float*)d_ws;
    float* sal    = ws;                        // 131072 floats
    float* cumsel = ws + (size_t)B_ * T_;      // 512 floats
    float* lift   = cumsel + B_ * P_;          // 131072 floats

    k1_sal<<<dim3((B_ * T_) / 256), dim3(256), 0, stream>>>(x, W1, b1, W2, b2, sal, ystar);
    k2_scan<<<dim3(B_), dim3(256), 0, stream>>>(sal, cumsel);
    k3a_lift<<<dim3((B_ * P_) / 4), dim3(256), 0, stream>>>(x, sal, cumsel, Wl, bl, mu, sg, lift);
    k3b_tok<<<dim3(B_ * 2 * 4), dim3(256), 0, stream>>>(lift, Wp, bp, tokens);
}

// Round 2
// 725.133 us; speedup vs baseline: 5.1554x; 5.1554x over previous
//
#include <hip/hip_runtime.h>
#include <hip/hip_bf16.h>
#include <math.h>

// Problem constants
#define B_ 32
#define T_ 4096
#define D_ 256
#define H_ 64
#define A_ 259
#define K_ 256
#define M_ 1024
#define P_ 16
#define STEP_ 273   // idx[i] = 273*i exactly (4095/15)

// ---------------------------------------------------------------------------
// K1: sal[b,t] = sigmoid(relu(x@W1+b1)@W2 + b2), plus y_star write.
// One thread per row. W1/b1/W2 are read with WAVE-UNIFORM global addresses so
// the compiler emits s_load (SGPR) for them: the inner loop is pure
// v_fmac_f32 h, s_w, v_x — no LDS, no per-weight VGPRs, no spills.
// x row read as float4 with one-chunk-ahead prefetch.
// ---------------------------------------------------------------------------
__global__ __launch_bounds__(256, 2) void k1_sal(
    const float* __restrict__ x, const float* __restrict__ W1,
    const float* __restrict__ b1, const float* __restrict__ W2,
    const float* __restrict__ b2, float* __restrict__ sal,
    float* __restrict__ ystar)
{
    const int row = blockIdx.x * 256 + threadIdx.x;
    const float4* xr = (const float4*)(x + (size_t)row * D_);

    float h[H_];
    #pragma unroll
    for (int j = 0; j < H_; ++j) h[j] = b1[j];          // uniform -> s_load

    // 16 chunks of 16 d-values (4 float4s), one-chunk-ahead prefetch
    float4 buf[4];
    #pragma unroll
    for (int q = 0; q < 4; ++q) buf[q] = xr[q];

    #pragma unroll 1
    for (int ch = 0; ch < 16; ++ch) {
        float4 nbuf[4];
        if (ch < 15) {
            #pragma unroll
            for (int q = 0; q < 4; ++q) nbuf[q] = xr[(ch + 1) * 4 + q];
        }
        #pragma unroll
        for (int q = 0; q < 4; ++q) {
            const float xv[4] = {buf[q].x, buf[q].y, buf[q].z, buf[q].w};
            #pragma unroll
            for (int dd = 0; dd < 4; ++dd) {
                const float* w = W1 + (size_t)(ch * 16 + q * 4 + dd) * H_; // uniform addr
                #pragma unroll
                for (int j = 0; j < H_; ++j)
                    h[j] = fmaf(xv[dd], w[j], h[j]);    // v_fmac vdst, sgpr, vgpr
            }
        }
        if (ch < 15) {
            #pragma unroll
            for (int q = 0; q < 4; ++q) buf[q] = nbuf[q];
        }
    }

    float score = b2[0];
    #pragma unroll
    for (int j = 0; j < H_; ++j) score = fmaf(fmaxf(h[j], 0.f), W2[j], score);
    const float s = 1.f / (1.f + __expf(-score));
    sal[row] = s;

    const int t = row & (T_ - 1);
    ystar[row] = (t % STEP_ == 0) ? 1.f : 0.f;
}

// ---------------------------------------------------------------------------
// K2: per-batch inclusive cumsum of sal, sampled at the 16 idx positions.
// ---------------------------------------------------------------------------
__global__ __launch_bounds__(256) void k2_scan(
    const float* __restrict__ sal, float* __restrict__ cumsel)
{
    __shared__ float vals[T_];
    __shared__ float tsum[256];
    const int b = blockIdx.x;
    const int t = threadIdx.x;

    const float4* sp = (const float4*)(sal + (size_t)b * T_);
    float v[16];
    #pragma unroll
    for (int q = 0; q < 4; ++q) {
        float4 f = sp[t * 4 + q];
        v[q*4+0] = f.x; v[q*4+1] = f.y; v[q*4+2] = f.z; v[q*4+3] = f.w;
    }
    float run = 0.f;
    #pragma unroll
    for (int k = 0; k < 16; ++k) { run += v[k]; v[k] = run; }

    tsum[t] = run;
    __syncthreads();
    float val = run;
    for (int off = 1; off < 256; off <<= 1) {
        float add = (t >= off) ? tsum[t - off] : 0.f;
        __syncthreads();
        val += add;
        tsum[t] = val;
        __syncthreads();
    }
    const float offset = val - run;   // exclusive prefix of thread totals
    #pragma unroll
    for (int k = 0; k < 16; ++k) vals[t * 16 + k] = offset + v[k];
    __syncthreads();
    if (t < P_) cumsel[b * P_ + t] = vals[STEP_ * t] * (1.0f / (float)T_);
}

// ---------------------------------------------------------------------------
// K3a: lifted = tanh(z @ Wl + bl) for the 512 selected rows. 4 rows per block.
// ---------------------------------------------------------------------------
__global__ __launch_bounds__(256) void k3a_lift(
    const float* __restrict__ x, const float* __restrict__ sal,
    const float* __restrict__ cumsel, const float* __restrict__ Wl,
    const float* __restrict__ bl, const float* __restrict__ mu,
    const float* __restrict__ sigma, float* __restrict__ lift)
{
    __shared__ float z[4][260];
    __shared__ float red[4];
    const int t = threadIdx.x;

    #pragma unroll 1
    for (int r = 0; r < 4; ++r) {
        const int s = blockIdx.x * 4 + r;
        const int b = s >> 4, i = s & 15;
        const int pos = STEP_ * i;
        const float* xrow = x + ((size_t)b * T_ + pos) * D_;
        const float xv = xrow[t];
        const float sv = sal[b * T_ + pos];
        const float tn = (float)pos * (1.0f / (float)T_);
        const float cv = cumsel[b * P_ + i];

        float p = xv * xv;
        if (t == 0) p += sv * sv + tn * tn + cv * cv;
        float w = p;
        #pragma unroll
        for (int off = 32; off > 0; off >>= 1) w += __shfl_down(w, off, 64);
        __syncthreads();
        if ((t & 63) == 0) red[t >> 6] = w;
        __syncthreads();
        const float ss = red[0] + red[1] + red[2] + red[3];
        const float inv = 1.0f / (sqrtf(ss) + 1e-6f);

        z[r][t] = (xv * inv - mu[t]) / sigma[t];
        if (t < 3) {
            const float e = (t == 0) ? sv : (t == 1) ? tn : cv;
            z[r][256 + t] = (e * inv - mu[256 + t]) / sigma[256 + t];
        }
    }
    __syncthreads();

    const int k = t;
    float acc0 = bl[k];
    float acc1 = acc0, acc2 = acc0, acc3 = acc0;
    #pragma unroll 4
    for (int a = 0; a < A_; ++a) {
        const float w = Wl[a * K_ + k];      // coalesced across threads
        acc0 = fmaf(z[0][a], w, acc0);       // z reads are LDS broadcasts
        acc1 = fmaf(z[1][a], w, acc1);
        acc2 = fmaf(z[2][a], w, acc2);
        acc3 = fmaf(z[3][a], w, acc3);
    }
    const size_t base = (size_t)blockIdx.x * 4 * K_;
    lift[base + 0 * K_ + k] = tanhf(acc0);
    lift[base + 1 * K_ + k] = tanhf(acc1);
    lift[base + 2 * K_ + k] = tanhf(acc2);
    lift[base + 3 * K_ + k] = tanhf(acc3);
}

// ---------------------------------------------------------------------------
// K3b: tokens = lifted @ Wp + bp.
// ---------------------------------------------------------------------------
__global__ __launch_bounds__(256) void k3b_tok(
    const float* __restrict__ lift, const float* __restrict__ Wp,
    const float* __restrict__ bp, float* __restrict__ tokens)
{
    __shared__ float ls[8 * K_];
    const int t = threadIdx.x;
    const int mt = blockIdx.x & 3;
    const int rh = (blockIdx.x >> 2) & 1;
    const int b  = blockIdx.x >> 3;
    const int s0 = b * P_ + rh * 8;

    const float4* lg = (const float4*)(lift + (size_t)s0 * K_);
    float4* lsl = (float4*)ls;
    #pragma unroll
    for (int q = 0; q < 2; ++q) lsl[t + q * 256] = lg[t + q * 256];
    __syncthreads();

    const int m = mt * 256 + t;
    float acc[8];
    const float bv = bp[m];
    #pragma unroll
    for (int r = 0; r < 8; ++r) acc[r] = bv;

    #pragma unroll 4
    for (int c = 0; c < K_; ++c) {
        const float w = Wp[c * M_ + m];      // coalesced across threads
        #pragma unroll
        for (int r = 0; r < 8; ++r) acc[r] = fmaf(ls[r * K_ + c], w, acc[r]);
    }
    #pragma unroll
    for (int r = 0; r < 8; ++r) tokens[(size_t)(s0 + r) * M_ + m] = acc[r];
}

// ---------------------------------------------------------------------------
extern "C" void kernel_launch(void* const* d_in, const int* in_sizes, int n_in,
                              void* d_out, int out_size, void* d_ws, size_t ws_size,
                              hipStream_t stream)
{
    (void)in_sizes; (void)n_in; (void)out_size; (void)ws_size;
    const float* x  = (const float*)d_in[0];
    const float* W1 = (const float*)d_in[1];
    const float* b1 = (const float*)d_in[2];
    const float* W2 = (const float*)d_in[3];
    const float* b2 = (const float*)d_in[4];
    const float* Wl = (const float*)d_in[5];
    const float* bl = (const float*)d_in[6];
    const float* mu = (const float*)d_in[7];
    const float* sg = (const float*)d_in[8];
    const float* Wp = (const float*)d_in[9];
    const float* bp = (const float*)d_in[10];

    float* out    = (float*)d_out;
    float* tokens = out;                        // B*P*M = 524288 floats
    float* ystar  = out + (size_t)B_ * P_ * M_; // B*T  = 131072 floats

    float* ws     = (float*)d_ws;
    float* sal    = ws;                         // 131072 floats
    float* cumsel = ws + (size_t)B_ * T_;       // 512 floats
    float* lift   = cumsel + B_ * P_;           // 131072 floats

    k1_sal<<<dim3((B_ * T_) / 256), dim3(256), 0, stream>>>(x, W1, b1, W2, b2, sal, ystar);
    k2_scan<<<dim3(B_), dim3(256), 0, stream>>>(sal, cumsel);
    k3a_lift<<<dim3((B_ * P_) / 4), dim3(256), 0, stream>>>(x, sal, cumsel, Wl, bl, mu, sg, lift);
    k3b_tok<<<dim3(B_ * 2 * 4), dim3(256), 0, stream>>>(lift, Wp, bp, tokens);
}

// Round 3
// 379.658 us; speedup vs baseline: 9.8467x; 1.9100x over previous
//
#include <hip/hip_runtime.h>
#include <hip/hip_bf16.h>
#include <math.h>

// Problem constants
#define B_ 32
#define T_ 4096
#define D_ 256
#define H_ 64
#define A_ 259
#define K_ 256
#define M_ 1024
#define P_ 16
#define STEP_ 273   // idx[i] = 273*i exactly (4095/15)

typedef __attribute__((ext_vector_type(8))) short bf16x8;
typedef __attribute__((ext_vector_type(4))) float f32x4;

__device__ __forceinline__ short f32_to_bf16_rne(float f) {
    unsigned u = __builtin_bit_cast(unsigned, f);
    unsigned r = (u + 0x7fffu + ((u >> 16) & 1u)) >> 16;
    return (short)r;
}

// ---------------------------------------------------------------------------
// K1 (MFMA): sal[b,t] = sigmoid(relu(x@W1+b1)@W2 + b2).
// Wave = 16 rows x 64 h-cols. W1 staged once per block into LDS in B-fragment
// order (one ds_read_b128 per fragment). x read 32B/lane contiguous, converted
// to bf16 in-register. 2048 blocks -> 8 blocks/CU wanted (LDS allows 5).
// ---------------------------------------------------------------------------
__global__ __launch_bounds__(256) void k1_sal(
    const float* __restrict__ x, const float* __restrict__ W1,
    const float* __restrict__ b1, const float* __restrict__ W2,
    const float* __restrict__ b2, float* __restrict__ sal)
{
    // w1f[kt][nt][lane] = 8 bf16: B[k=kt*32+(lane>>4)*8+j][n=nt*16+(lane&15)]
    __shared__ short w1f[8][4][64 * 8];      // 32 KB
    const int tid = threadIdx.x;

    #pragma unroll
    for (int i = 0; i < 8; ++i) {
        const int e = tid + i * 256;         // 0..2047
        const int lane = e & 63;
        const int ktnt = e >> 6;             // 0..31
        const int kt = ktnt >> 2, nt = ktnt & 3;
        const int n  = nt * 16 + (lane & 15);
        const int k0 = kt * 32 + (lane >> 4) * 8;
        bf16x8 v;
        #pragma unroll
        for (int j = 0; j < 8; ++j)
            v[j] = f32_to_bf16_rne(W1[(size_t)(k0 + j) * H_ + n]);
        *(bf16x8*)&w1f[kt][nt][lane * 8] = v;
    }
    __syncthreads();

    const int wave = tid >> 6, lane = tid & 63;
    const int m = lane & 15, q = lane >> 4;
    const int rowbase = blockIdx.x * 64 + wave * 16;
    const float* xrow = x + (size_t)(rowbase + m) * D_ + q * 8;

    f32x4 acc[4] = {{0,0,0,0},{0,0,0,0},{0,0,0,0},{0,0,0,0}};

    #pragma unroll
    for (int kt = 0; kt < 8; ++kt) {
        const float4 p0 = *(const float4*)(xrow + kt * 32);
        const float4 p1 = *(const float4*)(xrow + kt * 32 + 4);
        bf16x8 a;
        a[0] = f32_to_bf16_rne(p0.x); a[1] = f32_to_bf16_rne(p0.y);
        a[2] = f32_to_bf16_rne(p0.z); a[3] = f32_to_bf16_rne(p0.w);
        a[4] = f32_to_bf16_rne(p1.x); a[5] = f32_to_bf16_rne(p1.y);
        a[6] = f32_to_bf16_rne(p1.z); a[7] = f32_to_bf16_rne(p1.w);
        #pragma unroll
        for (int nt = 0; nt < 4; ++nt) {
            const bf16x8 bfr = *(const bf16x8*)&w1f[kt][nt][lane * 8];
            acc[nt] = __builtin_amdgcn_mfma_f32_16x16x32_bf16(a, bfr, acc[nt], 0, 0, 0);
        }
    }

    // Epilogue: lane holds cols n=nt*16+m, rows q*4+reg (verified C/D layout).
    float part[4];
    #pragma unroll
    for (int reg = 0; reg < 4; ++reg) {
        float s = 0.f;
        #pragma unroll
        for (int nt = 0; nt < 4; ++nt) {
            const int n = nt * 16 + m;
            const float hv = acc[nt][reg] + b1[n];
            s = fmaf(fmaxf(hv, 0.f), W2[n], s);
        }
        part[reg] = s;
    }
    #pragma unroll
    for (int off = 1; off < 16; off <<= 1) {
        #pragma unroll
        for (int reg = 0; reg < 4; ++reg)
            part[reg] += __shfl_xor(part[reg], off, 64);
    }
    const int r3 = m & 3;
    const float myv = (r3 == 0) ? part[0] : (r3 == 1) ? part[1]
                    : (r3 == 2) ? part[2] : part[3];
    if (m < 4) {
        const float score = myv + b2[0];
        sal[rowbase + q * 4 + m] = 1.f / (1.f + __expf(-score));
    }
}

// ---------------------------------------------------------------------------
// K2: per-batch inclusive cumsum of sal, sampled at the 16 idx positions.
// Also writes y_star (each thread owns 16 contiguous t positions).
// ---------------------------------------------------------------------------
__global__ __launch_bounds__(256) void k2_scan(
    const float* __restrict__ sal, float* __restrict__ cumsel,
    float* __restrict__ ystar)
{
    __shared__ float vals[T_];
    __shared__ float tsum[256];
    const int b = blockIdx.x;
    const int t = threadIdx.x;

    const float4* sp = (const float4*)(sal + (size_t)b * T_);
    float v[16];
    #pragma unroll
    for (int q = 0; q < 4; ++q) {
        float4 f = sp[t * 4 + q];
        v[q*4+0] = f.x; v[q*4+1] = f.y; v[q*4+2] = f.z; v[q*4+3] = f.w;
    }
    float run = 0.f;
    #pragma unroll
    for (int k = 0; k < 16; ++k) { run += v[k]; v[k] = run; }

    tsum[t] = run;
    __syncthreads();
    float val = run;
    for (int off = 1; off < 256; off <<= 1) {
        float add = (t >= off) ? tsum[t - off] : 0.f;
        __syncthreads();
        val += add;
        tsum[t] = val;
        __syncthreads();
    }
    const float offset = val - run;   // exclusive prefix of thread totals
    #pragma unroll
    for (int k = 0; k < 16; ++k) vals[t * 16 + k] = offset + v[k];

    // y_star: this thread owns t-positions t*16 .. t*16+15 of batch b
    float ys[16];
    #pragma unroll
    for (int k = 0; k < 16; ++k)
        ys[k] = (((t * 16 + k) % STEP_) == 0) ? 1.f : 0.f;
    float4* yo = (float4*)(ystar + (size_t)b * T_ + t * 16);
    #pragma unroll
    for (int q = 0; q < 4; ++q)
        yo[q] = make_float4(ys[q*4+0], ys[q*4+1], ys[q*4+2], ys[q*4+3]);

    __syncthreads();
    if (t < P_) cumsel[b * P_ + t] = vals[STEP_ * t] * (1.0f / (float)T_);
}

// ---------------------------------------------------------------------------
// K3a: lifted = tanh(z @ Wl + bl) for the 512 selected rows. 4 rows per block.
// ---------------------------------------------------------------------------
__global__ __launch_bounds__(256) void k3a_lift(
    const float* __restrict__ x, const float* __restrict__ sal,
    const float* __restrict__ cumsel, const float* __restrict__ Wl,
    const float* __restrict__ bl, const float* __restrict__ mu,
    const float* __restrict__ sigma, float* __restrict__ lift)
{
    __shared__ float z[4][260];
    __shared__ float red[4];
    const int t = threadIdx.x;

    #pragma unroll 1
    for (int r = 0; r < 4; ++r) {
        const int s = blockIdx.x * 4 + r;
        const int b = s >> 4, i = s & 15;
        const int pos = STEP_ * i;
        const float* xrow = x + ((size_t)b * T_ + pos) * D_;
        const float xv = xrow[t];
        const float sv = sal[b * T_ + pos];
        const float tn = (float)pos * (1.0f / (float)T_);
        const float cv = cumsel[b * P_ + i];

        float p = xv * xv;
        if (t == 0) p += sv * sv + tn * tn + cv * cv;
        float w = p;
        #pragma unroll
        for (int off = 32; off > 0; off >>= 1) w += __shfl_down(w, off, 64);
        __syncthreads();
        if ((t & 63) == 0) red[t >> 6] = w;
        __syncthreads();
        const float ss = red[0] + red[1] + red[2] + red[3];
        const float inv = 1.0f / (sqrtf(ss) + 1e-6f);

        z[r][t] = (xv * inv - mu[t]) / sigma[t];
        if (t < 3) {
            const float e = (t == 0) ? sv : (t == 1) ? tn : cv;
            z[r][256 + t] = (e * inv - mu[256 + t]) / sigma[256 + t];
        }
    }
    __syncthreads();

    const int k = t;
    float acc0 = bl[k];
    float acc1 = acc0, acc2 = acc0, acc3 = acc0;
    #pragma unroll 4
    for (int a = 0; a < A_; ++a) {
        const float w = Wl[a * K_ + k];      // coalesced across threads
        acc0 = fmaf(z[0][a], w, acc0);       // z reads are LDS broadcasts
        acc1 = fmaf(z[1][a], w, acc1);
        acc2 = fmaf(z[2][a], w, acc2);
        acc3 = fmaf(z[3][a], w, acc3);
    }
    const size_t base = (size_t)blockIdx.x * 4 * K_;
    lift[base + 0 * K_ + k] = tanhf(acc0);
    lift[base + 1 * K_ + k] = tanhf(acc1);
    lift[base + 2 * K_ + k] = tanhf(acc2);
    lift[base + 3 * K_ + k] = tanhf(acc3);
}

// ---------------------------------------------------------------------------
// K3b: tokens = lifted @ Wp + bp.
// ---------------------------------------------------------------------------
__global__ __launch_bounds__(256) void k3b_tok(
    const float* __restrict__ lift, const float* __restrict__ Wp,
    const float* __restrict__ bp, float* __restrict__ tokens)
{
    __shared__ float ls[8 * K_];
    const int t = threadIdx.x;
    const int mt = blockIdx.x & 3;
    const int rh = (blockIdx.x >> 2) & 1;
    const int b  = blockIdx.x >> 3;
    const int s0 = b * P_ + rh * 8;

    const float4* lg = (const float4*)(lift + (size_t)s0 * K_);
    float4* lsl = (float4*)ls;
    #pragma unroll
    for (int q = 0; q < 2; ++q) lsl[t + q * 256] = lg[t + q * 256];
    __syncthreads();

    const int m = mt * 256 + t;
    float acc[8];
    const float bv = bp[m];
    #pragma unroll
    for (int r = 0; r < 8; ++r) acc[r] = bv;

    #pragma unroll 4
    for (int c = 0; c < K_; ++c) {
        const float w = Wp[c * M_ + m];      // coalesced across threads
        #pragma unroll
        for (int r = 0; r < 8; ++r) acc[r] = fmaf(ls[r * K_ + c], w, acc[r]);
    }
    #pragma unroll
    for (int r = 0; r < 8; ++r) tokens[(size_t)(s0 + r) * M_ + m] = acc[r];
}

// ---------------------------------------------------------------------------
extern "C" void kernel_launch(void* const* d_in, const int* in_sizes, int n_in,
                              void* d_out, int out_size, void* d_ws, size_t ws_size,
                              hipStream_t stream)
{
    (void)in_sizes; (void)n_in; (void)out_size; (void)ws_size;
    const float* x  = (const float*)d_in[0];
    const float* W1 = (const float*)d_in[1];
    const float* b1 = (const float*)d_in[2];
    const float* W2 = (const float*)d_in[3];
    const float* b2 = (const float*)d_in[4];
    const float* Wl = (const float*)d_in[5];
    const float* bl = (const float*)d_in[6];
    const float* mu = (const float*)d_in[7];
    const float* sg = (const float*)d_in[8];
    const float* Wp = (const float*)d_in[9];
    const float* bp = (const float*)d_in[10];

    float* out    = (float*)d_out;
    float* tokens = out;                        // B*P*M = 524288 floats
    float* ystar  = out + (size_t)B_ * P_ * M_; // B*T  = 131072 floats

    float* ws     = (float*)d_ws;
    float* sal    = ws;                         // 131072 floats
    float* cumsel = ws + (size_t)B_ * T_;       // 512 floats
    float* lift   = cumsel + B_ * P_;           // 131072 floats

    k1_sal<<<dim3((B_ * T_) / 64), dim3(256), 0, stream>>>(x, W1, b1, W2, b2, sal);
    k2_scan<<<dim3(B_), dim3(256), 0, stream>>>(sal, cumsel, ystar);
    k3a_lift<<<dim3((B_ * P_) / 4), dim3(256), 0, stream>>>(x, sal, cumsel, Wl, bl, mu, sg, lift);
    k3b_tok<<<dim3(B_ * 2 * 4), dim3(256), 0, stream>>>(lift, Wp, bp, tokens);
}

// Round 4
// 247.724 us; speedup vs baseline: 15.0909x; 1.5326x over previous
//
#include <hip/hip_runtime.h>
#include <hip/hip_bf16.h>
#include <math.h>

// Problem constants
#define B_ 32
#define T_ 4096
#define D_ 256
#define H_ 64
#define A_ 259
#define K_ 256
#define M_ 1024
#define P_ 16
#define STEP_ 273   // idx[i] = 273*i exactly (4095/15)

typedef __attribute__((ext_vector_type(8))) short bf16x8;
typedef __attribute__((ext_vector_type(4))) float f32x4;

__device__ __forceinline__ short f32_to_bf16_rne(float f) {
    unsigned u = __builtin_bit_cast(unsigned, f);
    unsigned r = (u + 0x7fffu + ((u >> 16) & 1u)) >> 16;
    return (short)r;
}

// ---------------------------------------------------------------------------
// K1 (MFMA): sal[b,t] = sigmoid(relu(x@W1+b1)@W2 + b2).
// Wave = 16 rows x 64 h-cols; 4 x (16x16x32) MFMA per K-step.
// ---------------------------------------------------------------------------
__global__ __launch_bounds__(256) void k1_sal(
    const float* __restrict__ x, const float* __restrict__ W1,
    const float* __restrict__ b1, const float* __restrict__ W2,
    const float* __restrict__ b2, float* __restrict__ sal)
{
    // w1f[kt][nt][lane] = 8 bf16: B[k=kt*32+(lane>>4)*8+j][n=nt*16+(lane&15)]
    __shared__ short w1f[8][4][64 * 8];      // 32 KB
    const int tid = threadIdx.x;

    #pragma unroll
    for (int i = 0; i < 8; ++i) {
        const int e = tid + i * 256;         // 0..2047
        const int lane = e & 63;
        const int ktnt = e >> 6;             // 0..31
        const int kt = ktnt >> 2, nt = ktnt & 3;
        const int n  = nt * 16 + (lane & 15);
        const int k0 = kt * 32 + (lane >> 4) * 8;
        bf16x8 v;
        #pragma unroll
        for (int j = 0; j < 8; ++j)
            v[j] = f32_to_bf16_rne(W1[(size_t)(k0 + j) * H_ + n]);
        *(bf16x8*)&w1f[kt][nt][lane * 8] = v;
    }
    __syncthreads();

    const int wave = tid >> 6, lane = tid & 63;
    const int m = lane & 15, q = lane >> 4;
    const int rowbase = blockIdx.x * 64 + wave * 16;
    const float* xrow = x + (size_t)(rowbase + m) * D_ + q * 8;

    f32x4 acc[4] = {{0,0,0,0},{0,0,0,0},{0,0,0,0},{0,0,0,0}};

    #pragma unroll
    for (int kt = 0; kt < 8; ++kt) {
        const float4 p0 = *(const float4*)(xrow + kt * 32);
        const float4 p1 = *(const float4*)(xrow + kt * 32 + 4);
        bf16x8 a;
        a[0] = f32_to_bf16_rne(p0.x); a[1] = f32_to_bf16_rne(p0.y);
        a[2] = f32_to_bf16_rne(p0.z); a[3] = f32_to_bf16_rne(p0.w);
        a[4] = f32_to_bf16_rne(p1.x); a[5] = f32_to_bf16_rne(p1.y);
        a[6] = f32_to_bf16_rne(p1.z); a[7] = f32_to_bf16_rne(p1.w);
        #pragma unroll
        for (int nt = 0; nt < 4; ++nt) {
            const bf16x8 bfr = *(const bf16x8*)&w1f[kt][nt][lane * 8];
            acc[nt] = __builtin_amdgcn_mfma_f32_16x16x32_bf16(a, bfr, acc[nt], 0, 0, 0);
        }
    }

    // Epilogue: lane holds cols n=nt*16+m, rows q*4+reg (verified C/D layout).
    float part[4];
    #pragma unroll
    for (int reg = 0; reg < 4; ++reg) {
        float s = 0.f;
        #pragma unroll
        for (int nt = 0; nt < 4; ++nt) {
            const int n = nt * 16 + m;
            const float hv = acc[nt][reg] + b1[n];
            s = fmaf(fmaxf(hv, 0.f), W2[n], s);
        }
        part[reg] = s;
    }
    #pragma unroll
    for (int off = 1; off < 16; off <<= 1) {
        #pragma unroll
        for (int reg = 0; reg < 4; ++reg)
            part[reg] += __shfl_xor(part[reg], off, 64);
    }
    const int r3 = m & 3;
    const float myv = (r3 == 0) ? part[0] : (r3 == 1) ? part[1]
                    : (r3 == 2) ? part[2] : part[3];
    if (m < 4) {
        const float score = myv + b2[0];
        sal[rowbase + q * 4 + m] = 1.f / (1.f + __expf(-score));
    }
}

// ---------------------------------------------------------------------------
// K2: per-batch inclusive cumsum of sal, sampled at the 16 idx positions.
// Also writes y_star.
// ---------------------------------------------------------------------------
__global__ __launch_bounds__(256) void k2_scan(
    const float* __restrict__ sal, float* __restrict__ cumsel,
    float* __restrict__ ystar)
{
    __shared__ float vals[T_];
    __shared__ float tsum[256];
    const int b = blockIdx.x;
    const int t = threadIdx.x;

    const float4* sp = (const float4*)(sal + (size_t)b * T_);
    float v[16];
    #pragma unroll
    for (int q = 0; q < 4; ++q) {
        float4 f = sp[t * 4 + q];
        v[q*4+0] = f.x; v[q*4+1] = f.y; v[q*4+2] = f.z; v[q*4+3] = f.w;
    }
    float run = 0.f;
    #pragma unroll
    for (int k = 0; k < 16; ++k) { run += v[k]; v[k] = run; }

    tsum[t] = run;
    __syncthreads();
    float val = run;
    for (int off = 1; off < 256; off <<= 1) {
        float add = (t >= off) ? tsum[t - off] : 0.f;
        __syncthreads();
        val += add;
        tsum[t] = val;
        __syncthreads();
    }
    const float offset = val - run;   // exclusive prefix of thread totals
    #pragma unroll
    for (int k = 0; k < 16; ++k) vals[t * 16 + k] = offset + v[k];

    // y_star: this thread owns t-positions t*16 .. t*16+15 of batch b
    float ys[16];
    #pragma unroll
    for (int k = 0; k < 16; ++k)
        ys[k] = (((t * 16 + k) % STEP_) == 0) ? 1.f : 0.f;
    float4* yo = (float4*)(ystar + (size_t)b * T_ + t * 16);
    #pragma unroll
    for (int q = 0; q < 4; ++q)
        yo[q] = make_float4(ys[q*4+0], ys[q*4+1], ys[q*4+2], ys[q*4+3]);

    __syncthreads();
    if (t < P_) cumsel[b * P_ + t] = vals[STEP_ * t] * (1.0f / (float)T_);
}

// ---------------------------------------------------------------------------
// K3a: lifted = tanh(z @ Wl + bl) for the 512 selected rows. 4 rows/block.
// Phase 1: wave r normalizes row r (pure shuffle reduction, no block syncs).
// Phase 2: a-loop (259) split across 4 waves (~65 each); lane loads float4 of
//          Wl (k=4*lane+c), acc[4 rows][4 k]. Partials in LDS, then reduce.
// ---------------------------------------------------------------------------
__global__ __launch_bounds__(256) void k3a_lift(
    const float* __restrict__ x, const float* __restrict__ sal,
    const float* __restrict__ cumsel, const float* __restrict__ Wl,
    const float* __restrict__ bl, const float* __restrict__ mu,
    const float* __restrict__ sigma, float* __restrict__ lift)
{
    __shared__ float z[4][260];
    __shared__ float part[4 * 4 * 256];      // [wave][row][k], 16 KB
    const int tid = threadIdx.x;
    const int wave = tid >> 6, lane = tid & 63;

    // ---- Phase 1: wave r owns selected row r ----
    {
        const int r = wave;
        const int s = blockIdx.x * 4 + r;
        const int b = s >> 4, i = s & 15;
        const int pos = STEP_ * i;
        const float* xrow = x + ((size_t)b * T_ + pos) * D_;
        const float4 xv = *(const float4*)(xrow + 4 * lane);
        const float sv = sal[b * T_ + pos];
        const float tn = (float)pos * (1.0f / (float)T_);
        const float cv = cumsel[b * P_ + i];

        float p = xv.x*xv.x + xv.y*xv.y + xv.z*xv.z + xv.w*xv.w;
        #pragma unroll
        for (int off = 32; off > 0; off >>= 1) p += __shfl_xor(p, off, 64);
        const float ss = p + sv * sv + tn * tn + cv * cv;
        const float inv = 1.0f / (sqrtf(ss) + 1e-6f);

        const float4 muv = *(const float4*)(mu + 4 * lane);
        const float4 sgv = *(const float4*)(sigma + 4 * lane);
        z[r][4*lane+0] = (xv.x * inv - muv.x) / sgv.x;
        z[r][4*lane+1] = (xv.y * inv - muv.y) / sgv.y;
        z[r][4*lane+2] = (xv.z * inv - muv.z) / sgv.z;
        z[r][4*lane+3] = (xv.w * inv - muv.w) / sgv.w;
        if (lane < 3) {
            const float e = (lane == 0) ? sv : (lane == 1) ? tn : cv;
            z[r][256 + lane] = (e * inv - mu[256 + lane]) / sigma[256 + lane];
        }
    }
    __syncthreads();

    // ---- Phase 2: wave-split a-loop ----
    const int a0 = wave * 65;
    const int a1 = (wave == 3) ? A_ : a0 + 65;
    f32x4 acc[4] = {{0,0,0,0},{0,0,0,0},{0,0,0,0},{0,0,0,0}};
    const float4* Wl4 = (const float4*)Wl;   // row stride 64 float4

    #pragma unroll 4
    for (int a = a0; a < a1; ++a) {
        const float4 wv = Wl4[a * 64 + lane];
        #pragma unroll
        for (int r = 0; r < 4; ++r) {
            const float zv = z[r][a];        // LDS broadcast
            acc[r][0] = fmaf(zv, wv.x, acc[r][0]);
            acc[r][1] = fmaf(zv, wv.y, acc[r][1]);
            acc[r][2] = fmaf(zv, wv.z, acc[r][2]);
            acc[r][3] = fmaf(zv, wv.w, acc[r][3]);
        }
    }
    {
        f32x4* p4 = (f32x4*)part;
        #pragma unroll
        for (int r = 0; r < 4; ++r)
            p4[(wave * 4 + r) * 64 + lane] = acc[r];
    }
    __syncthreads();

    // ---- Phase 3: reduce + tanh + store ----
    const int r = tid >> 6;                  // 0..3
    const size_t base = (size_t)blockIdx.x * 4 * K_;
    #pragma unroll
    for (int j = 0; j < 4; ++j) {
        const int k = lane + 64 * j;
        float val = bl[k];
        #pragma unroll
        for (int w = 0; w < 4; ++w)
            val += part[(w * 4 + r) * 256 + k];
        lift[base + r * K_ + k] = tanhf(val);
    }
}

// ---------------------------------------------------------------------------
// K3b: tokens = lifted @ Wp + bp. Block = (b, rowhalf of 8, mtile of 256).
// c-loop (256) split across 4 waves; lane loads float4 of Wp (4 m-cols);
// acc[8] float4. Partials in 32 KB LDS, reduce with bias once.
// ---------------------------------------------------------------------------
__global__ __launch_bounds__(256) void k3b_tok(
    const float* __restrict__ lift, const float* __restrict__ Wp,
    const float* __restrict__ bp, float* __restrict__ tokens)
{
    __shared__ float ls[8 * K_];             // 8 KB
    __shared__ float part[4 * 8 * 256];      // [wave][row][m], 32 KB
    const int tid = threadIdx.x;
    const int wave = tid >> 6, lane = tid & 63;
    const int mt = blockIdx.x & 3;
    const int rh = (blockIdx.x >> 2) & 1;
    const int b  = blockIdx.x >> 3;
    const int s0 = b * P_ + rh * 8;
    const int m0 = mt * 256;

    const float4* lg = (const float4*)(lift + (size_t)s0 * K_);
    float4* lsl = (float4*)ls;
    lsl[tid] = lg[tid];
    lsl[tid + 256] = lg[tid + 256];
    __syncthreads();

    f32x4 acc[8] = {{0,0,0,0},{0,0,0,0},{0,0,0,0},{0,0,0,0},
                    {0,0,0,0},{0,0,0,0},{0,0,0,0},{0,0,0,0}};
    const float4* Wp4 = (const float4*)(Wp + m0);   // row stride 256 float4

    #pragma unroll 2
    for (int c4 = 0; c4 < 16; ++c4) {
        const int c = wave * 64 + c4 * 4;
        float4 lsv[8];
        #pragma unroll
        for (int r = 0; r < 8; ++r)
            lsv[r] = *(const float4*)&ls[r * K_ + c];   // ds_read_b128 bcast
        #pragma unroll
        for (int cc = 0; cc < 4; ++cc) {
            const float4 wv = Wp4[(size_t)(c + cc) * 256 + lane];
            #pragma unroll
            for (int r = 0; r < 8; ++r) {
                const float lv = (cc == 0) ? lsv[r].x : (cc == 1) ? lsv[r].y
                               : (cc == 2) ? lsv[r].z : lsv[r].w;
                acc[r][0] = fmaf(lv, wv.x, acc[r][0]);
                acc[r][1] = fmaf(lv, wv.y, acc[r][1]);
                acc[r][2] = fmaf(lv, wv.z, acc[r][2]);
                acc[r][3] = fmaf(lv, wv.w, acc[r][3]);
            }
        }
    }
    {
        f32x4* p4 = (f32x4*)part;
        #pragma unroll
        for (int r = 0; r < 8; ++r)
            p4[(wave * 8 + r) * 64 + lane] = acc[r];
    }
    __syncthreads();

    // Reduce: thread t owns m-col t for all 8 rows.
    const float bv = bp[m0 + tid];
    #pragma unroll
    for (int r = 0; r < 8; ++r) {
        float val = bv;
        #pragma unroll
        for (int w = 0; w < 4; ++w)
            val += part[(w * 8 + r) * 256 + tid];
        tokens[(size_t)(s0 + r) * M_ + m0 + tid] = val;
    }
}

// ---------------------------------------------------------------------------
extern "C" void kernel_launch(void* const* d_in, const int* in_sizes, int n_in,
                              void* d_out, int out_size, void* d_ws, size_t ws_size,
                              hipStream_t stream)
{
    (void)in_sizes; (void)n_in; (void)out_size; (void)ws_size;
    const float* x  = (const float*)d_in[0];
    const float* W1 = (const float*)d_in[1];
    const float* b1 = (const float*)d_in[2];
    const float* W2 = (const float*)d_in[3];
    const float* b2 = (const float*)d_in[4];
    const float* Wl = (const float*)d_in[5];
    const float* bl = (const float*)d_in[6];
    const float* mu = (const float*)d_in[7];
    const float* sg = (const float*)d_in[8];
    const float* Wp = (const float*)d_in[9];
    const float* bp = (const float*)d_in[10];

    float* out    = (float*)d_out;
    float* tokens = out;                        // B*P*M = 524288 floats
    float* ystar  = out + (size_t)B_ * P_ * M_; // B*T  = 131072 floats

    float* ws     = (float*)d_ws;
    float* sal    = ws;                         // 131072 floats
    float* cumsel = ws + (size_t)B_ * T_;       // 512 floats
    float* lift   = cumsel + B_ * P_;           // 131072 floats

    k1_sal<<<dim3((B_ * T_) / 64), dim3(256), 0, stream>>>(x, W1, b1, W2, b2, sal);
    k2_scan<<<dim3(B_), dim3(256), 0, stream>>>(sal, cumsel, ystar);
    k3a_lift<<<dim3((B_ * P_) / 4), dim3(256), 0, stream>>>(x, sal, cumsel, Wl, bl, mu, sg, lift);
    k3b_tok<<<dim3(B_ * 2 * 4), dim3(256), 0, stream>>>(lift, Wp, bp, tokens);
}